// Round 6
// baseline (1329.799 us; speedup 1.0000x reference)
//
#include <hip/hip_runtime.h>
#include <hip/hip_fp16.h>
#include <hip/hip_cooperative_groups.h>
#include <cstddef>

namespace cg = cooperative_groups;

// ---------------------------------------------------------------------------
// CrystalGNN (SchNet-style). R6: cooperative single-kernel with occupancy-
// queried grid + standalone-dispatch fallback. Shared __device__ phase fns:
//   setup : deg=0; gstart (batch sorted); gemm0 (x=emb lookup, h=x@W1_0+b1_0)
//   hist  : deg[dst]++
//   scan  : 3-phase exclusive scan -> off[N+1], cursor[N]
//   scatter: edge -> slot sorted by dst; payload int4{src, A, B},
//            A=exp(-1.125 d^2), B=exp(1.5 d); RBF_r = A*B^r*C_r with C_r
//            folded into per-lane filter weights (conv = pure FMA Horner)
//   gemm  : h = x @ W1[l] + b1[l]  (fp16 out)
//   conv  : wave/node 8-deep gather pipeline + residual + W2(shfl) + softplus
//   pool  : contiguous per-graph mean;  head: 2 graphs/block MLP
// ---------------------------------------------------------------------------

// C_r = exp(-0.5 r^2), r = 0..9
#define RBF_C0 1.0f
#define RBF_C1 0.60653065971f
#define RBF_C2 0.13533528324f
#define RBF_C3 0.011108996538f
#define RBF_C4 3.3546262790e-4f
#define RBF_C5 3.7266531720e-6f
#define RBF_C6 1.5229979745e-8f
#define RBF_C7 2.2897348457e-11f
#define RBF_C8 1.2664165549e-14f
#define RBF_C9 2.5767043600e-18f

struct GArgs {
    const int* x_ids; const int* src; const int* dst; const float* eattr; const int* batch;
    const float* emb; const float* W1; const float* b1; const float* We; const float* be;
    const float* W2; const float* b2;
    const float* Ws; const float* bs;
    const float* Wbg1; const float* bbg1; const float* Wbg2; const float* bbg2;
    const float* Weh1; const float* beh1; const float* Weh2; const float* beh2;
    float* x; __half* h; float* cmean; int4* psort;
    int* deg; int* off; int* cursor; int* bsum; int* gstart;
    float* out;
    int n_nodes, n_edges, n_graphs, nchunks;
};

__device__ __forceinline__ float softplusf(float v) {
    return fmaxf(v, 0.0f) + log1pf(__expf(-fabsf(v)));
}

__device__ __forceinline__ float row_gemv(const float4* __restrict__ xr,
                                          const float w[64], float bj) {
    float a0 = bj, a1 = 0.f, a2 = 0.f, a3 = 0.f;
#pragma unroll
    for (int q = 0; q < 4; ++q) {
        float4 v0 = xr[4 * q + 0], v1 = xr[4 * q + 1];
        float4 v2 = xr[4 * q + 2], v3 = xr[4 * q + 3];
        a0 = fmaf(v0.x, w[16 * q + 0], a0);  a0 = fmaf(v0.y, w[16 * q + 1], a0);
        a0 = fmaf(v0.z, w[16 * q + 2], a0);  a0 = fmaf(v0.w, w[16 * q + 3], a0);
        a1 = fmaf(v1.x, w[16 * q + 4], a1);  a1 = fmaf(v1.y, w[16 * q + 5], a1);
        a1 = fmaf(v1.z, w[16 * q + 6], a1);  a1 = fmaf(v1.w, w[16 * q + 7], a1);
        a2 = fmaf(v2.x, w[16 * q + 8], a2);  a2 = fmaf(v2.y, w[16 * q + 9], a2);
        a2 = fmaf(v2.z, w[16 * q + 10], a2); a2 = fmaf(v2.w, w[16 * q + 11], a2);
        a3 = fmaf(v3.x, w[16 * q + 12], a3); a3 = fmaf(v3.y, w[16 * q + 13], a3);
        a3 = fmaf(v3.z, w[16 * q + 14], a3); a3 = fmaf(v3.w, w[16 * q + 15], a3);
    }
    return (a0 + a1) + (a2 + a3);
}

__device__ __forceinline__ float filt_ab(const float wp[10], float bj, float A, float B) {
    float P = wp[9];
    P = fmaf(B, P, wp[8]); P = fmaf(B, P, wp[7]); P = fmaf(B, P, wp[6]);
    P = fmaf(B, P, wp[5]); P = fmaf(B, P, wp[4]); P = fmaf(B, P, wp[3]);
    P = fmaf(B, P, wp[2]); P = fmaf(B, P, wp[1]); P = fmaf(B, P, wp[0]);
    return fmaf(A, P, bj);
}

// ---------------- phase device functions ----------------

__device__ void dv_setup(const GArgs& a, int tid, int nth, int lane, int gw, int nw) {
    for (int i = tid; i < a.n_nodes; i += nth) a.deg[i] = 0;
    for (int n = tid; n < a.n_nodes; n += nth) {
        int b = a.batch[n];
        int prev = (n == 0) ? -1 : a.batch[n - 1];
        for (int g2 = prev + 1; g2 <= b; ++g2) a.gstart[g2] = n;
        if (n == a.n_nodes - 1)
            for (int g2 = b + 1; g2 <= a.n_graphs; ++g2) a.gstart[g2] = a.n_nodes;
    }
    float w[64];
#pragma unroll
    for (int k = 0; k < 64; ++k) w[k] = a.W1[k * 64 + lane];
    float bj = a.b1[lane];
    for (int n = gw; n < a.n_nodes; n += nw) {
        int id = __builtin_amdgcn_readfirstlane(a.x_ids[n]);
        const float4* xr = (const float4*)(a.emb + (size_t)id * 64);
        float v = row_gemv(xr, w, bj);
        a.x[(size_t)n * 64 + lane] = a.emb[(size_t)id * 64 + lane];
        a.h[(size_t)n * 64 + lane] = __float2half(v);
    }
}

__device__ void dv_hist(const GArgs& a, int tid, int nth) {
    for (int e = tid; e < a.n_edges; e += nth) atomicAdd(&a.deg[a.dst[e]], 1);
}

__device__ void dv_scan_a(const GArgs& a, int bid, int t, int* s) {
    int i = bid * 256 + t;
    int v = (i < a.n_nodes) ? a.deg[i] : 0;
    s[t] = v;
    __syncthreads();
    for (int off = 1; off < 256; off <<= 1) {
        int tv = (t >= off) ? s[t - off] : 0;
        __syncthreads();
        s[t] += tv;
        __syncthreads();
    }
    if (i < a.n_nodes) a.off[i + 1] = s[t];
    if (t == 255) a.bsum[bid] = s[255];
}

__device__ void dv_scan_b(const GArgs& a, int t, int* s) {
    int v = (t < a.nchunks) ? a.bsum[t] : 0;
    s[t] = v;
    __syncthreads();
    for (int off = 1; off < 256; off <<= 1) {
        int tv = (t >= off) ? s[t - off] : 0;
        __syncthreads();
        s[t] += tv;
        __syncthreads();
    }
    if (t < a.nchunks) a.bsum[t] = s[t] - v;  // exclusive
}

__device__ void dv_scan_c(const GArgs& a, int tid, int nth) {
    for (int i = tid; i < a.n_nodes; i += nth) {
        int incl = a.off[i + 1] + a.bsum[i >> 8];
        a.off[i + 1] = incl;
        a.cursor[i] = incl - a.deg[i];
    }
    if (tid == 0) a.off[0] = 0;
}

__device__ void dv_scatter(const GArgs& a, int tid, int nth) {
    for (int e = tid; e < a.n_edges; e += nth) {
        int t = a.dst[e];
        int pos = atomicAdd(&a.cursor[t], 1);
        float d = a.eattr[e];
        float A = __expf(-1.125f * d * d);
        float B = __expf(1.5f * d);
        a.psort[pos] = make_int4(a.src[e], __float_as_int(A), __float_as_int(B), 0);
    }
}

__device__ void dv_gemm(const GArgs& a, int l, int lane, int gw, int nw) {
    float w[64];
#pragma unroll
    for (int k = 0; k < 64; ++k) w[k] = a.W1[l * 4096 + k * 64 + lane];
    float bj = a.b1[l * 64 + lane];
    for (int n = gw; n < a.n_nodes; n += nw) {
        const float4* xr = (const float4*)(a.x + (size_t)n * 64);
        a.h[(size_t)n * 64 + lane] = __float2half(row_gemv(xr, w, bj));
    }
}

__device__ void dv_conv(const GArgs& a, int l, int lane, int gw, int nw) {
    const float C[10] = {RBF_C0, RBF_C1, RBF_C2, RBF_C3, RBF_C4,
                         RBF_C5, RBF_C6, RBF_C7, RBF_C8, RBF_C9};
    float wp[10];
#pragma unroll
    for (int r = 0; r < 10; ++r) wp[r] = a.We[l * 640 + r * 64 + lane] * C[r];
    float bj  = a.be[l * 64 + lane];
    float b2j = a.b2[l * 64 + lane];
    const float* W2l = a.W2 + l * 4096;
    const int4* ps = a.psort;

    for (int n = gw; n < a.n_nodes; n += nw) {
        int k0 = a.off[n], k1 = a.off[n + 1];
        float acc = 0.0f;
        int k = k0;
        for (; k + 8 <= k1; k += 8) {
            int4 p0 = ps[k + 0], p1 = ps[k + 1], p2 = ps[k + 2], p3 = ps[k + 3];
            int4 p4 = ps[k + 4], p5 = ps[k + 5], p6 = ps[k + 6], p7 = ps[k + 7];
            float g0 = __half2float(a.h[(size_t)p0.x * 64 + lane]);
            float g1 = __half2float(a.h[(size_t)p1.x * 64 + lane]);
            float g2 = __half2float(a.h[(size_t)p2.x * 64 + lane]);
            float g3 = __half2float(a.h[(size_t)p3.x * 64 + lane]);
            float g4 = __half2float(a.h[(size_t)p4.x * 64 + lane]);
            float g5 = __half2float(a.h[(size_t)p5.x * 64 + lane]);
            float g6 = __half2float(a.h[(size_t)p6.x * 64 + lane]);
            float g7 = __half2float(a.h[(size_t)p7.x * 64 + lane]);
            acc = fmaf(g0, filt_ab(wp, bj, __int_as_float(p0.y), __int_as_float(p0.z)), acc);
            acc = fmaf(g1, filt_ab(wp, bj, __int_as_float(p1.y), __int_as_float(p1.z)), acc);
            acc = fmaf(g2, filt_ab(wp, bj, __int_as_float(p2.y), __int_as_float(p2.z)), acc);
            acc = fmaf(g3, filt_ab(wp, bj, __int_as_float(p3.y), __int_as_float(p3.z)), acc);
            acc = fmaf(g4, filt_ab(wp, bj, __int_as_float(p4.y), __int_as_float(p4.z)), acc);
            acc = fmaf(g5, filt_ab(wp, bj, __int_as_float(p5.y), __int_as_float(p5.z)), acc);
            acc = fmaf(g6, filt_ab(wp, bj, __int_as_float(p6.y), __int_as_float(p6.z)), acc);
            acc = fmaf(g7, filt_ab(wp, bj, __int_as_float(p7.y), __int_as_float(p7.z)), acc);
        }
        for (; k + 4 <= k1; k += 4) {
            int4 p0 = ps[k + 0], p1 = ps[k + 1], p2 = ps[k + 2], p3 = ps[k + 3];
            float g0 = __half2float(a.h[(size_t)p0.x * 64 + lane]);
            float g1 = __half2float(a.h[(size_t)p1.x * 64 + lane]);
            float g2 = __half2float(a.h[(size_t)p2.x * 64 + lane]);
            float g3 = __half2float(a.h[(size_t)p3.x * 64 + lane]);
            acc = fmaf(g0, filt_ab(wp, bj, __int_as_float(p0.y), __int_as_float(p0.z)), acc);
            acc = fmaf(g1, filt_ab(wp, bj, __int_as_float(p1.y), __int_as_float(p1.z)), acc);
            acc = fmaf(g2, filt_ab(wp, bj, __int_as_float(p2.y), __int_as_float(p2.z)), acc);
            acc = fmaf(g3, filt_ab(wp, bj, __int_as_float(p3.y), __int_as_float(p3.z)), acc);
        }
        for (; k < k1; ++k) {
            int4 p = ps[k];
            float g = __half2float(a.h[(size_t)p.x * 64 + lane]);
            acc = fmaf(g, filt_ab(wp, bj, __int_as_float(p.y), __int_as_float(p.z)), acc);
        }
        float o0 = b2j + a.x[(size_t)n * 64 + lane];
        float o1 = 0.f, o2 = 0.f, o3 = 0.f;
#pragma unroll 4
        for (int kk = 0; kk < 16; ++kk) {
            o0 = fmaf(__shfl(acc, kk),      W2l[(kk)      * 64 + lane], o0);
            o1 = fmaf(__shfl(acc, kk + 16), W2l[(kk + 16) * 64 + lane], o1);
            o2 = fmaf(__shfl(acc, kk + 32), W2l[(kk + 32) * 64 + lane], o2);
            o3 = fmaf(__shfl(acc, kk + 48), W2l[(kk + 48) * 64 + lane], o3);
        }
        a.x[(size_t)n * 64 + lane] = softplusf((o0 + o1) + (o2 + o3));
    }
}

__device__ void dv_pool(const GArgs& a, int bid, int nbid, int t, float* s) {
    int j = t & 63, part = t >> 6;
    for (int g = bid; g < a.n_graphs; g += nbid) {
        int s0 = a.gstart[g], s1 = a.gstart[g + 1];
        float acc = 0.0f;
        for (int n = s0 + part; n < s1; n += 4) acc += a.x[(size_t)n * 64 + j];
        s[t] = acc;
        __syncthreads();
        if (part == 0) {
            float v = s[j] + s[64 + j] + s[128 + j] + s[192 + j];
            a.cmean[(size_t)g * 64 + j] = v / fmaxf((float)(s1 - s0), 1.0f);
        }
        __syncthreads();
    }
}

__device__ void dv_head(const GArgs& a, int bid, int nbid, int t, float* s) {
    // s: 384 floats. c[2*64] at 0, h1[2*128] at 128.
    for (int gp = bid; gp * 2 < a.n_graphs; gp += nbid) {
        int sub = t >> 7, tt = t & 127, g = gp * 2 + sub;
        bool valid = g < a.n_graphs;
        float* c  = s + sub * 64;
        float* h1 = s + 128 + sub * 128;
        if (valid && tt < 64) c[tt] = a.cmean[(size_t)g * 64 + tt];
        __syncthreads();
        if (valid) {
            float av = a.bs[tt];
#pragma unroll 8
            for (int k = 0; k < 64; ++k) av = fmaf(c[k], a.Ws[k * 128 + tt], av);
            h1[tt] = fmaxf(av, 0.0f);
        }
        __syncthreads();
        if (valid) {
            const float* W1p = (tt < 64) ? a.Wbg1 : a.Weh1;
            const float* b1p = (tt < 64) ? a.bbg1 : a.beh1;
            const float* W2p = (tt < 64) ? a.Wbg2 : a.Weh2;
            float b2v = (tt < 64) ? a.bbg2[0] : a.beh2[0];
            int ln = tt & 63;
            float a2 = b1p[ln];
#pragma unroll 8
            for (int k = 0; k < 128; ++k) a2 = fmaf(h1[k], W1p[k * 64 + ln], a2);
            a2 = fmaxf(a2, 0.0f);
            float pr = a2 * W2p[ln];
#pragma unroll
            for (int off = 32; off > 0; off >>= 1) pr += __shfl_down(pr, off);
            if (ln == 0) a.out[(tt < 64 ? 0 : a.n_graphs) + g] = pr + b2v;
        }
        __syncthreads();
    }
}

// ---------------- cooperative fused kernel ----------------
__global__ __launch_bounds__(256, 4) void k_all(GArgs a) {
    cg::grid_group grid = cg::this_grid();
    __shared__ float smem[384];
    const int tid  = blockIdx.x * blockDim.x + threadIdx.x;
    const int nth  = gridDim.x * blockDim.x;
    const int lane = threadIdx.x & 63;
    const int gw   = tid >> 6;
    const int nw   = nth >> 6;

    dv_setup(a, tid, nth, lane, gw, nw);
    grid.sync();
    dv_hist(a, tid, nth);
    grid.sync();
    if ((int)blockIdx.x < a.nchunks) dv_scan_a(a, blockIdx.x, threadIdx.x, (int*)smem);
    grid.sync();
    if (blockIdx.x == 0) dv_scan_b(a, threadIdx.x, (int*)smem);
    grid.sync();
    dv_scan_c(a, tid, nth);
    grid.sync();
    dv_scatter(a, tid, nth);
    grid.sync();
    for (int l = 0; l < 3; ++l) {
        if (l > 0) {
            dv_gemm(a, l, lane, gw, nw);
            grid.sync();
        }
        dv_conv(a, l, lane, gw, nw);
        grid.sync();
    }
    dv_pool(a, blockIdx.x, gridDim.x, threadIdx.x, smem);
    grid.sync();
    dv_head(a, blockIdx.x, gridDim.x, threadIdx.x, smem);
}

// ---------------- standalone fallback kernels ----------------
__global__ void k_setup_sa(GArgs a) {
    int tid = blockIdx.x * blockDim.x + threadIdx.x, nth = gridDim.x * blockDim.x;
    dv_setup(a, tid, nth, threadIdx.x & 63, tid >> 6, nth >> 6);
}
__global__ void k_hist_sa(GArgs a) {
    dv_hist(a, blockIdx.x * blockDim.x + threadIdx.x, gridDim.x * blockDim.x);
}
__global__ void k_scana_sa(GArgs a) {
    __shared__ int s[256];
    dv_scan_a(a, blockIdx.x, threadIdx.x, s);
}
__global__ void k_scanb_sa(GArgs a) {
    __shared__ int s[256];
    dv_scan_b(a, threadIdx.x, s);
}
__global__ void k_scanc_sa(GArgs a) {
    dv_scan_c(a, blockIdx.x * blockDim.x + threadIdx.x, gridDim.x * blockDim.x);
}
__global__ void k_scatter_sa(GArgs a) {
    dv_scatter(a, blockIdx.x * blockDim.x + threadIdx.x, gridDim.x * blockDim.x);
}
__global__ void k_gemm_sa(GArgs a, int l) {
    int tid = blockIdx.x * blockDim.x + threadIdx.x, nth = gridDim.x * blockDim.x;
    dv_gemm(a, l, threadIdx.x & 63, tid >> 6, nth >> 6);
}
__global__ void k_conv_sa(GArgs a, int l) {
    int tid = blockIdx.x * blockDim.x + threadIdx.x, nth = gridDim.x * blockDim.x;
    dv_conv(a, l, threadIdx.x & 63, tid >> 6, nth >> 6);
}
__global__ void k_pool_sa(GArgs a) {
    __shared__ float s[256];
    dv_pool(a, blockIdx.x, gridDim.x, threadIdx.x, s);
}
__global__ void k_head_sa(GArgs a) {
    __shared__ float s[384];
    dv_head(a, blockIdx.x, gridDim.x, threadIdx.x, s);
}

static void launch_fallback(const GArgs& a, hipStream_t stream) {
    GArgs aa = a;
    int nbE = (a.n_edges + 255) / 256;
    int nbN = (a.n_nodes + 255) / 256;
    hipLaunchKernelGGL(k_setup_sa, dim3(1024), dim3(256), 0, stream, aa);
    hipLaunchKernelGGL(k_hist_sa, dim3(nbE), dim3(256), 0, stream, aa);
    hipLaunchKernelGGL(k_scana_sa, dim3(a.nchunks), dim3(256), 0, stream, aa);
    hipLaunchKernelGGL(k_scanb_sa, dim3(1), dim3(256), 0, stream, aa);
    hipLaunchKernelGGL(k_scanc_sa, dim3(nbN), dim3(256), 0, stream, aa);
    hipLaunchKernelGGL(k_scatter_sa, dim3(nbE), dim3(256), 0, stream, aa);
    for (int l = 0; l < 3; ++l) {
        if (l > 0) hipLaunchKernelGGL(k_gemm_sa, dim3(1024), dim3(256), 0, stream, aa, l);
        hipLaunchKernelGGL(k_conv_sa, dim3(4096), dim3(256), 0, stream, aa, l);
    }
    hipLaunchKernelGGL(k_pool_sa, dim3(a.n_graphs), dim3(256), 0, stream, aa);
    hipLaunchKernelGGL(k_head_sa, dim3((a.n_graphs + 1) / 2), dim3(256), 0, stream, aa);
}

extern "C" void kernel_launch(void* const* d_in, const int* in_sizes, int n_in,
                              void* d_out, int out_size, void* d_ws, size_t ws_size,
                              hipStream_t stream) {
    GArgs a;
    a.x_ids = (const int*)d_in[0];
    const int* eidx = (const int*)d_in[1];
    a.eattr = (const float*)d_in[2];
    a.batch = (const int*)d_in[3];
    a.emb   = (const float*)d_in[4];
    a.W1    = (const float*)d_in[5];
    a.b1    = (const float*)d_in[6];
    a.We    = (const float*)d_in[7];
    a.be    = (const float*)d_in[8];
    a.W2    = (const float*)d_in[9];
    a.b2    = (const float*)d_in[10];
    a.Ws    = (const float*)d_in[11];
    a.bs    = (const float*)d_in[12];
    a.Wbg1  = (const float*)d_in[13];
    a.bbg1  = (const float*)d_in[14];
    a.Wbg2  = (const float*)d_in[15];
    a.bbg2  = (const float*)d_in[16];
    a.Weh1  = (const float*)d_in[17];
    a.beh1  = (const float*)d_in[18];
    a.Weh2  = (const float*)d_in[19];
    a.beh2  = (const float*)d_in[20];

    a.n_nodes  = in_sizes[0];
    a.n_edges  = in_sizes[2];
    a.n_graphs = out_size / 2;
    a.nchunks  = (a.n_nodes + 255) / 256;
    a.src = eidx;
    a.dst = eidx + a.n_edges;

    char* p = (char*)d_ws;
    a.x      = (float*)p;   p += (size_t)a.n_nodes * 64 * sizeof(float);
    a.h      = (__half*)p;  p += (size_t)a.n_nodes * 64 * sizeof(__half);
    a.cmean  = (float*)p;   p += (size_t)a.n_graphs * 64 * sizeof(float);
    a.psort  = (int4*)p;    p += (size_t)a.n_edges * sizeof(int4);
    a.deg    = (int*)p;     p += (size_t)a.n_nodes * sizeof(int);
    a.off    = (int*)p;     p += (size_t)(a.n_nodes + 1) * sizeof(int);
    a.cursor = (int*)p;     p += (size_t)a.n_nodes * sizeof(int);
    a.bsum   = (int*)p;     p += 256 * sizeof(int);
    a.gstart = (int*)p;     p += (size_t)(a.n_graphs + 1) * sizeof(int);
    a.out    = (float*)d_out;

    // Size the cooperative grid from MEASURED occupancy (host-only queries,
    // deterministic, capture-safe). Fall back to standalone dispatches if
    // co-residency is too low or the cooperative launch is refused.
    int maxB = 0;
    hipError_t qerr = hipOccupancyMaxActiveBlocksPerMultiprocessor(
        &maxB, (const void*)k_all, 256, 0);
    int nCU = 0;
    hipError_t derr = hipDeviceGetAttribute(&nCU, hipDeviceAttributeMultiprocessorCount, 0);

    bool coop_ok = (qerr == hipSuccess) && (derr == hipSuccess) && (maxB >= 2) && (nCU > 0);
    if (coop_ok) {
        int bpc = maxB < 8 ? maxB : 8;
        long grid = (long)bpc * nCU;
        if (grid > 2048) grid = 2048;
        if (grid < (long)a.nchunks) grid = a.nchunks;  // scan_a needs >= nchunks blocks
        void* args[] = {&a};
        hipError_t lerr = hipLaunchCooperativeKernel((const void*)k_all, dim3((int)grid),
                                                     dim3(256), args, 0, stream);
        if (lerr == hipSuccess) return;
    }
    launch_fallback(a, stream);
}

// Round 7
// 479.428 us; speedup vs baseline: 2.7737x; 2.7737x over previous
//
#include <hip/hip_runtime.h>
#include <hip/hip_fp16.h>
#include <cstddef>

// ---------------------------------------------------------------------------
// CrystalGNN (SchNet-style). R7: multi-dispatch (grid.sync is ~100µs/XCD-flush
// on MI355X — R6 measured), spill-free conv.
//   memset deg; k_pre (hist + gstart); scan a/b/c; k_scatter (payload
//   int4{src*64, A, B, 0}, A=exp(-1.125d^2), B=exp(1.5d), RBF=A*B^r*C_r with
//   C_r folded into filter weights); per layer: gemm (h=x@W1+b1, fp16) then
//   conv (8-deep gather pipeline, 32-bit addrs, LDS-staged W2 epilogue,
//   __launch_bounds__(256,4) => 128 VGPR, no spill); fused pool+head.
// ---------------------------------------------------------------------------

// C_r = exp(-0.5 r^2), r = 0..9
#define RBF_C0 1.0f
#define RBF_C1 0.60653065971f
#define RBF_C2 0.13533528324f
#define RBF_C3 0.011108996538f
#define RBF_C4 3.3546262790e-4f
#define RBF_C5 3.7266531720e-6f
#define RBF_C6 1.5229979745e-8f
#define RBF_C7 2.2897348457e-11f
#define RBF_C8 1.2664165549e-14f
#define RBF_C9 2.5767043600e-18f

__device__ __forceinline__ float softplusf(float v) {
    return fmaxf(v, 0.0f) + log1pf(__expf(-fabsf(v)));
}

__device__ __forceinline__ float row_gemv(const float4* __restrict__ xr,
                                          const float w[64], float bj) {
    float a0 = bj, a1 = 0.f, a2 = 0.f, a3 = 0.f;
#pragma unroll
    for (int q = 0; q < 4; ++q) {
        float4 v0 = xr[4 * q + 0], v1 = xr[4 * q + 1];
        float4 v2 = xr[4 * q + 2], v3 = xr[4 * q + 3];
        a0 = fmaf(v0.x, w[16 * q + 0], a0);  a0 = fmaf(v0.y, w[16 * q + 1], a0);
        a0 = fmaf(v0.z, w[16 * q + 2], a0);  a0 = fmaf(v0.w, w[16 * q + 3], a0);
        a1 = fmaf(v1.x, w[16 * q + 4], a1);  a1 = fmaf(v1.y, w[16 * q + 5], a1);
        a1 = fmaf(v1.z, w[16 * q + 6], a1);  a1 = fmaf(v1.w, w[16 * q + 7], a1);
        a2 = fmaf(v2.x, w[16 * q + 8], a2);  a2 = fmaf(v2.y, w[16 * q + 9], a2);
        a2 = fmaf(v2.z, w[16 * q + 10], a2); a2 = fmaf(v2.w, w[16 * q + 11], a2);
        a3 = fmaf(v3.x, w[16 * q + 12], a3); a3 = fmaf(v3.y, w[16 * q + 13], a3);
        a3 = fmaf(v3.z, w[16 * q + 14], a3); a3 = fmaf(v3.w, w[16 * q + 15], a3);
    }
    return (a0 + a1) + (a2 + a3);
}

__device__ __forceinline__ float filt_ab(const float wp[10], float bj, float A, float B) {
    float P = wp[9];
    P = fmaf(B, P, wp[8]); P = fmaf(B, P, wp[7]); P = fmaf(B, P, wp[6]);
    P = fmaf(B, P, wp[5]); P = fmaf(B, P, wp[4]); P = fmaf(B, P, wp[3]);
    P = fmaf(B, P, wp[2]); P = fmaf(B, P, wp[1]); P = fmaf(B, P, wp[0]);
    return fmaf(A, P, bj);
}

// ---------------- hist + gstart (fused independent passes) ----------------
__global__ void k_pre(const int* __restrict__ dst, int* __restrict__ deg,
                      const int* __restrict__ batch, int* __restrict__ gstart,
                      int n_edges, int n_nodes, int n_graphs) {
    int tid = blockIdx.x * blockDim.x + threadIdx.x;
    if (tid < n_edges) atomicAdd(&deg[dst[tid]], 1);
    if (tid < n_nodes) {
        int b = batch[tid];
        int prev = (tid == 0) ? -1 : batch[tid - 1];
        for (int g = prev + 1; g <= b; ++g) gstart[g] = tid;
        if (tid == n_nodes - 1)
            for (int g = b + 1; g <= n_graphs; ++g) gstart[g] = n_nodes;
    }
}

// ---------------- scan ----------------
__global__ void k_scana(const int* __restrict__ deg, int* __restrict__ off_,
                        int* __restrict__ bsum, int n) {
    __shared__ int s[256];
    int i = blockIdx.x * 256 + threadIdx.x;
    int v = (i < n) ? deg[i] : 0;
    s[threadIdx.x] = v;
    __syncthreads();
    for (int off = 1; off < 256; off <<= 1) {
        int t = (threadIdx.x >= off) ? s[threadIdx.x - off] : 0;
        __syncthreads();
        s[threadIdx.x] += t;
        __syncthreads();
    }
    if (i < n) off_[i + 1] = s[threadIdx.x];
    if (threadIdx.x == 255) bsum[blockIdx.x] = s[255];
}

__global__ void k_scanb(int* __restrict__ bsum, int nb) {
    __shared__ int s[256];
    int v = ((int)threadIdx.x < nb) ? bsum[threadIdx.x] : 0;
    s[threadIdx.x] = v;
    __syncthreads();
    for (int off = 1; off < 256; off <<= 1) {
        int t = (threadIdx.x >= off) ? s[threadIdx.x - off] : 0;
        __syncthreads();
        s[threadIdx.x] += t;
        __syncthreads();
    }
    if ((int)threadIdx.x < nb) bsum[threadIdx.x] = s[threadIdx.x] - v;  // exclusive
}

__global__ void k_scanc(const int* __restrict__ deg, const int* __restrict__ bsum,
                        int* __restrict__ off_, int* __restrict__ cursor, int n) {
    int i = blockIdx.x * blockDim.x + threadIdx.x;
    if (i < n) {
        int incl = off_[i + 1] + bsum[i >> 8];
        off_[i + 1] = incl;
        cursor[i] = incl - deg[i];
    }
    if (i == 0) off_[0] = 0;
}

// ---------------- scatter: payload {src*64, A, B, 0} ----------------
__global__ void k_scatter(const int* __restrict__ src, const int* __restrict__ dst,
                          const float* __restrict__ dist, int* __restrict__ cursor,
                          int4* __restrict__ psort, int n_edges) {
    int e = blockIdx.x * blockDim.x + threadIdx.x;
    if (e >= n_edges) return;
    int t = dst[e];
    int pos = atomicAdd(&cursor[t], 1);
    float d = dist[e];
    float A = __expf(-1.125f * d * d);
    float B = __expf(1.5f * d);
    psort[pos] = make_int4(src[e] << 6, __float_as_int(A), __float_as_int(B), 0);
}

// ---------------- gemm0: x = emb[ids], h = x@W1_0 + b1_0 ----------------
__global__ __launch_bounds__(256, 4) void k_gemm0(
        const int* __restrict__ ids, const float* __restrict__ emb,
        const float* __restrict__ W, const float* __restrict__ bias,
        float* __restrict__ x, __half* __restrict__ h, int n_nodes) {
    int lane = threadIdx.x & 63;
    int gw = __builtin_amdgcn_readfirstlane((blockIdx.x * blockDim.x + threadIdx.x) >> 6);
    int nw = (gridDim.x * blockDim.x) >> 6;
    float w[64];
#pragma unroll
    for (int k = 0; k < 64; ++k) w[k] = W[k * 64 + lane];
    float bj = bias[lane];
    for (int n = gw; n < n_nodes; n += nw) {
        int id = __builtin_amdgcn_readfirstlane(ids[n]);
        const float4* xr = (const float4*)(emb + id * 64);
        float v = row_gemv(xr, w, bj);
        x[n * 64 + lane] = emb[id * 64 + lane];
        h[n * 64 + lane] = __float2half(v);
    }
}

// ---------------- gemm: h = x@W1_l + b1_l ----------------
__global__ __launch_bounds__(256, 4) void k_gemm(
        const float* __restrict__ X, const float* __restrict__ W,
        const float* __restrict__ bias, __half* __restrict__ Y, int n_nodes) {
    int lane = threadIdx.x & 63;
    int gw = __builtin_amdgcn_readfirstlane((blockIdx.x * blockDim.x + threadIdx.x) >> 6);
    int nw = (gridDim.x * blockDim.x) >> 6;
    float w[64];
#pragma unroll
    for (int k = 0; k < 64; ++k) w[k] = W[k * 64 + lane];
    float bj = bias[lane];
    for (int n = gw; n < n_nodes; n += nw) {
        const float4* xr = (const float4*)(X + n * 64);
        Y[n * 64 + lane] = __float2half(row_gemv(xr, w, bj));
    }
}

// ---------------- conv ----------------
__global__ __launch_bounds__(256, 4) void k_conv(
        const int4* __restrict__ ps, const int* __restrict__ off,
        const __half* __restrict__ h,
        const float* __restrict__ We, const float* __restrict__ be,
        const float* __restrict__ W2, const float* __restrict__ b2,
        float* __restrict__ x, int n_nodes) {
    __shared__ float sW2[4096];
    for (int i = threadIdx.x; i < 4096; i += 256) sW2[i] = W2[i];

    int lane = threadIdx.x & 63;
    int gw = __builtin_amdgcn_readfirstlane((blockIdx.x * blockDim.x + threadIdx.x) >> 6);
    int nw = (gridDim.x * blockDim.x) >> 6;

    const float C[10] = {RBF_C0, RBF_C1, RBF_C2, RBF_C3, RBF_C4,
                         RBF_C5, RBF_C6, RBF_C7, RBF_C8, RBF_C9};
    float wp[10];
#pragma unroll
    for (int r = 0; r < 10; ++r) wp[r] = We[r * 64 + lane] * C[r];
    float bj  = be[lane];
    float b2j = b2[lane];
    __syncthreads();

    for (int n = gw; n < n_nodes; n += nw) {
        int k0 = off[n], k1 = off[n + 1];
        float acc = 0.0f;
        int k = k0;
        for (; k + 8 <= k1; k += 8) {
            int4 p0 = ps[k + 0], p1 = ps[k + 1], p2 = ps[k + 2], p3 = ps[k + 3];
            int4 p4 = ps[k + 4], p5 = ps[k + 5], p6 = ps[k + 6], p7 = ps[k + 7];
            float g0 = __half2float(h[p0.x + lane]);
            float g1 = __half2float(h[p1.x + lane]);
            float g2 = __half2float(h[p2.x + lane]);
            float g3 = __half2float(h[p3.x + lane]);
            float g4 = __half2float(h[p4.x + lane]);
            float g5 = __half2float(h[p5.x + lane]);
            float g6 = __half2float(h[p6.x + lane]);
            float g7 = __half2float(h[p7.x + lane]);
            acc = fmaf(g0, filt_ab(wp, bj, __int_as_float(p0.y), __int_as_float(p0.z)), acc);
            acc = fmaf(g1, filt_ab(wp, bj, __int_as_float(p1.y), __int_as_float(p1.z)), acc);
            acc = fmaf(g2, filt_ab(wp, bj, __int_as_float(p2.y), __int_as_float(p2.z)), acc);
            acc = fmaf(g3, filt_ab(wp, bj, __int_as_float(p3.y), __int_as_float(p3.z)), acc);
            acc = fmaf(g4, filt_ab(wp, bj, __int_as_float(p4.y), __int_as_float(p4.z)), acc);
            acc = fmaf(g5, filt_ab(wp, bj, __int_as_float(p5.y), __int_as_float(p5.z)), acc);
            acc = fmaf(g6, filt_ab(wp, bj, __int_as_float(p6.y), __int_as_float(p6.z)), acc);
            acc = fmaf(g7, filt_ab(wp, bj, __int_as_float(p7.y), __int_as_float(p7.z)), acc);
        }
        for (; k + 4 <= k1; k += 4) {
            int4 p0 = ps[k + 0], p1 = ps[k + 1], p2 = ps[k + 2], p3 = ps[k + 3];
            float g0 = __half2float(h[p0.x + lane]);
            float g1 = __half2float(h[p1.x + lane]);
            float g2 = __half2float(h[p2.x + lane]);
            float g3 = __half2float(h[p3.x + lane]);
            acc = fmaf(g0, filt_ab(wp, bj, __int_as_float(p0.y), __int_as_float(p0.z)), acc);
            acc = fmaf(g1, filt_ab(wp, bj, __int_as_float(p1.y), __int_as_float(p1.z)), acc);
            acc = fmaf(g2, filt_ab(wp, bj, __int_as_float(p2.y), __int_as_float(p2.z)), acc);
            acc = fmaf(g3, filt_ab(wp, bj, __int_as_float(p3.y), __int_as_float(p3.z)), acc);
        }
        for (; k < k1; ++k) {
            int4 p = ps[k];
            float g = __half2float(h[p.x + lane]);
            acc = fmaf(g, filt_ab(wp, bj, __int_as_float(p.y), __int_as_float(p.z)), acc);
        }
        float o0 = b2j + x[n * 64 + lane];
        float o1 = 0.f, o2 = 0.f, o3 = 0.f;
#pragma unroll 4
        for (int kk = 0; kk < 16; ++kk) {
            o0 = fmaf(__shfl(acc, kk),      sW2[(kk)      * 64 + lane], o0);
            o1 = fmaf(__shfl(acc, kk + 16), sW2[(kk + 16) * 64 + lane], o1);
            o2 = fmaf(__shfl(acc, kk + 32), sW2[(kk + 32) * 64 + lane], o2);
            o3 = fmaf(__shfl(acc, kk + 48), sW2[(kk + 48) * 64 + lane], o3);
        }
        x[n * 64 + lane] = softplusf((o0 + o1) + (o2 + o3));
    }
}

// ---------------- fused pool + head: one block per graph ----------------
__global__ void k_poolhead(const float* __restrict__ x, const int* __restrict__ gstart,
                           const float* __restrict__ Ws, const float* __restrict__ bs,
                           const float* __restrict__ Wbg1, const float* __restrict__ bbg1,
                           const float* __restrict__ Wbg2, const float* __restrict__ bbg2,
                           const float* __restrict__ Weh1, const float* __restrict__ beh1,
                           const float* __restrict__ Weh2, const float* __restrict__ beh2,
                           float* __restrict__ out, int n_graphs) {
    __shared__ float red[256];
    __shared__ float c[64];
    __shared__ float h1[128];
    int g = blockIdx.x;
    int t = threadIdx.x, j = t & 63, part = t >> 6;
    int s0 = gstart[g], s1 = gstart[g + 1];
    float acc = 0.0f;
    for (int n = s0 + part; n < s1; n += 4) acc += x[n * 64 + j];
    red[t] = acc;
    __syncthreads();
    if (part == 0)
        c[j] = (red[j] + red[64 + j] + red[128 + j] + red[192 + j]) /
               fmaxf((float)(s1 - s0), 1.0f);
    __syncthreads();
    if (t < 128) {
        float av = bs[t];
#pragma unroll 8
        for (int k = 0; k < 64; ++k) av = fmaf(c[k], Ws[k * 128 + t], av);
        h1[t] = fmaxf(av, 0.0f);
    }
    __syncthreads();
    if (t < 128) {
        const float* W1p = (t < 64) ? Wbg1 : Weh1;
        const float* b1p = (t < 64) ? bbg1 : beh1;
        const float* W2p = (t < 64) ? Wbg2 : Weh2;
        float b2v = (t < 64) ? bbg2[0] : beh2[0];
        int ln = t & 63;
        float a2 = b1p[ln];
#pragma unroll 8
        for (int k = 0; k < 128; ++k) a2 = fmaf(h1[k], W1p[k * 64 + ln], a2);
        a2 = fmaxf(a2, 0.0f);
        float pr = a2 * W2p[ln];
#pragma unroll
        for (int off = 32; off > 0; off >>= 1) pr += __shfl_down(pr, off);
        if (ln == 0) out[(t < 64 ? 0 : n_graphs) + g] = pr + b2v;
    }
}

extern "C" void kernel_launch(void* const* d_in, const int* in_sizes, int n_in,
                              void* d_out, int out_size, void* d_ws, size_t ws_size,
                              hipStream_t stream) {
    const int*   x_ids = (const int*)d_in[0];
    const int*   eidx  = (const int*)d_in[1];
    const float* eattr = (const float*)d_in[2];
    const int*   batch = (const int*)d_in[3];
    const float* emb   = (const float*)d_in[4];
    const float* W1    = (const float*)d_in[5];
    const float* b1    = (const float*)d_in[6];
    const float* We    = (const float*)d_in[7];
    const float* be    = (const float*)d_in[8];
    const float* W2    = (const float*)d_in[9];
    const float* b2    = (const float*)d_in[10];
    const float* Ws_   = (const float*)d_in[11];
    const float* bs_   = (const float*)d_in[12];
    const float* Wbg1  = (const float*)d_in[13];
    const float* bbg1  = (const float*)d_in[14];
    const float* Wbg2  = (const float*)d_in[15];
    const float* bbg2  = (const float*)d_in[16];
    const float* Weh1  = (const float*)d_in[17];
    const float* beh1  = (const float*)d_in[18];
    const float* Weh2  = (const float*)d_in[19];
    const float* beh2  = (const float*)d_in[20];

    int n_nodes  = in_sizes[0];
    int n_edges  = in_sizes[2];
    int n_graphs = out_size / 2;
    const int* src = eidx;
    const int* dst = eidx + n_edges;

    char* p = (char*)d_ws;
    float* x     = (float*)p;   p += (size_t)n_nodes * 64 * sizeof(float);
    __half* h    = (__half*)p;  p += (size_t)n_nodes * 64 * sizeof(__half);
    int4* psort  = (int4*)p;    p += (size_t)n_edges * sizeof(int4);
    int* deg     = (int*)p;     p += (size_t)n_nodes * sizeof(int);
    int* off_    = (int*)p;     p += (size_t)(n_nodes + 1) * sizeof(int);
    int* cursor  = (int*)p;     p += (size_t)n_nodes * sizeof(int);
    int* bsum    = (int*)p;     p += 256 * sizeof(int);
    int* gstart  = (int*)p;     p += (size_t)(n_graphs + 1) * sizeof(int);
    float* out   = (float*)d_out;

    int nchunks = (n_nodes + 255) / 256;
    int nbE = (n_edges + 255) / 256;
    int nbN = (n_nodes + 255) / 256;
    int nbPre = (nbE > nbN) ? nbE : nbN;

    hipMemsetAsync(deg, 0, (size_t)n_nodes * sizeof(int), stream);
    k_pre<<<nbPre, 256, 0, stream>>>(dst, deg, batch, gstart, n_edges, n_nodes, n_graphs);
    k_scana<<<nchunks, 256, 0, stream>>>(deg, off_, bsum, n_nodes);
    k_scanb<<<1, 256, 0, stream>>>(bsum, nchunks);
    k_scanc<<<nbN, 256, 0, stream>>>(deg, bsum, off_, cursor, n_nodes);
    k_scatter<<<nbE, 256, 0, stream>>>(src, dst, eattr, cursor, psort, n_edges);

    k_gemm0<<<1024, 256, 0, stream>>>(x_ids, emb, W1, b1, x, h, n_nodes);
    for (int l = 0; l < 3; ++l) {
        if (l > 0)
            k_gemm<<<1024, 256, 0, stream>>>(x, W1 + l * 4096, b1 + l * 64, h, n_nodes);
        k_conv<<<4096, 256, 0, stream>>>(psort, off_, h,
                                         We + l * 640, be + l * 64,
                                         W2 + l * 4096, b2 + l * 64, x, n_nodes);
    }
    k_poolhead<<<n_graphs, 256, 0, stream>>>(x, gstart, Ws_, bs_, Wbg1, bbg1, Wbg2, bbg2,
                                             Weh1, beh1, Weh2, beh2, out, n_graphs);
}

// Round 8
// 435.492 us; speedup vs baseline: 3.0536x; 1.1009x over previous
//
#include <hip/hip_runtime.h>
#include <hip/hip_fp16.h>
#include <cstddef>

// ---------------------------------------------------------------------------
// CrystalGNN (SchNet-style). R8: 10 dispatches.
//   memset deg
//   k_pre     : hist deg[dst]++  +  gstart  +  x=emb[ids]  +  hA=x@W1_0+b1_0
//   scan a/b/c: exclusive scan -> off[N+1], cursor[N]
//   k_scatter : edge -> dst-sorted slot, payload int4{src*64, A, B, 0},
//               A=exp(-1.125 d^2), B=exp(1.5 d); RBF_r = A*B^r*C_r, C_r folded
//               into per-lane filter weights (conv hot loop = pure FMA)
//   k_conv ×3 : wave/node 8-deep gather pipeline (latency-bound ->
//               __launch_bounds__(256,6) = 24 waves/CU, no LDS);
//               epilogue: x=softplus(x+acc@W2+b2)  AND  h_next=x_new@W1'+b1'
//               (shfl row reuse; ping-pong hA/hB) -> no standalone gemms.
//   k_poolhead: per-graph mean + two 2-layer MLP heads.
// ---------------------------------------------------------------------------

// C_r = exp(-0.5 r^2), r = 0..9
#define RBF_C0 1.0f
#define RBF_C1 0.60653065971f
#define RBF_C2 0.13533528324f
#define RBF_C3 0.011108996538f
#define RBF_C4 3.3546262790e-4f
#define RBF_C5 3.7266531720e-6f
#define RBF_C6 1.5229979745e-8f
#define RBF_C7 2.2897348457e-11f
#define RBF_C8 1.2664165549e-14f
#define RBF_C9 2.5767043600e-18f

__device__ __forceinline__ float softplusf(float v) {
    return fmaxf(v, 0.0f) + log1pf(__expf(-fabsf(v)));
}

__device__ __forceinline__ float row_gemv(const float4* __restrict__ xr,
                                          const float w[64], float bj) {
    float a0 = bj, a1 = 0.f, a2 = 0.f, a3 = 0.f;
#pragma unroll
    for (int q = 0; q < 4; ++q) {
        float4 v0 = xr[4 * q + 0], v1 = xr[4 * q + 1];
        float4 v2 = xr[4 * q + 2], v3 = xr[4 * q + 3];
        a0 = fmaf(v0.x, w[16 * q + 0], a0);  a0 = fmaf(v0.y, w[16 * q + 1], a0);
        a0 = fmaf(v0.z, w[16 * q + 2], a0);  a0 = fmaf(v0.w, w[16 * q + 3], a0);
        a1 = fmaf(v1.x, w[16 * q + 4], a1);  a1 = fmaf(v1.y, w[16 * q + 5], a1);
        a1 = fmaf(v1.z, w[16 * q + 6], a1);  a1 = fmaf(v1.w, w[16 * q + 7], a1);
        a2 = fmaf(v2.x, w[16 * q + 8], a2);  a2 = fmaf(v2.y, w[16 * q + 9], a2);
        a2 = fmaf(v2.z, w[16 * q + 10], a2); a2 = fmaf(v2.w, w[16 * q + 11], a2);
        a3 = fmaf(v3.x, w[16 * q + 12], a3); a3 = fmaf(v3.y, w[16 * q + 13], a3);
        a3 = fmaf(v3.z, w[16 * q + 14], a3); a3 = fmaf(v3.w, w[16 * q + 15], a3);
    }
    return (a0 + a1) + (a2 + a3);
}

__device__ __forceinline__ float filt_ab(const float wp[10], float bj, float A, float B) {
    float P = wp[9];
    P = fmaf(B, P, wp[8]); P = fmaf(B, P, wp[7]); P = fmaf(B, P, wp[6]);
    P = fmaf(B, P, wp[5]); P = fmaf(B, P, wp[4]); P = fmaf(B, P, wp[3]);
    P = fmaf(B, P, wp[2]); P = fmaf(B, P, wp[1]); P = fmaf(B, P, wp[0]);
    return fmaf(A, P, bj);
}

// ---------------- hist + gstart + embed + gemm0 (independent passes) -------
__global__ void k_pre(const int* __restrict__ dst, int* __restrict__ deg,
                      const int* __restrict__ batch, int* __restrict__ gstart,
                      const int* __restrict__ ids, const float* __restrict__ emb,
                      const float* __restrict__ W1, const float* __restrict__ b1,
                      float* __restrict__ x, __half* __restrict__ hA,
                      int n_edges, int n_nodes, int n_graphs) {
    int tid = blockIdx.x * blockDim.x + threadIdx.x;
    int nth = gridDim.x * blockDim.x;
    for (int e = tid; e < n_edges; e += nth) atomicAdd(&deg[dst[e]], 1);
    for (int n = tid; n < n_nodes; n += nth) {
        int b = batch[n];
        int prev = (n == 0) ? -1 : batch[n - 1];
        for (int g = prev + 1; g <= b; ++g) gstart[g] = n;
        if (n == n_nodes - 1)
            for (int g = b + 1; g <= n_graphs; ++g) gstart[g] = n_nodes;
    }
    // gemm0: x = emb[ids], hA = x @ W1[0] + b1[0]
    int lane = threadIdx.x & 63;
    int gw = __builtin_amdgcn_readfirstlane(tid >> 6);
    int nw = nth >> 6;
    float w[64];
#pragma unroll
    for (int k = 0; k < 64; ++k) w[k] = W1[k * 64 + lane];
    float bj = b1[lane];
    for (int n = gw; n < n_nodes; n += nw) {
        int id = __builtin_amdgcn_readfirstlane(ids[n]);
        const float4* xr = (const float4*)(emb + id * 64);
        float v = row_gemv(xr, w, bj);
        x[n * 64 + lane] = emb[id * 64 + lane];
        hA[n * 64 + lane] = __float2half(v);
    }
}

// ---------------- scan ----------------
__global__ void k_scana(const int* __restrict__ deg, int* __restrict__ off_,
                        int* __restrict__ bsum, int n) {
    __shared__ int s[256];
    int i = blockIdx.x * 256 + threadIdx.x;
    int v = (i < n) ? deg[i] : 0;
    s[threadIdx.x] = v;
    __syncthreads();
    for (int off = 1; off < 256; off <<= 1) {
        int t = (threadIdx.x >= off) ? s[threadIdx.x - off] : 0;
        __syncthreads();
        s[threadIdx.x] += t;
        __syncthreads();
    }
    if (i < n) off_[i + 1] = s[threadIdx.x];
    if (threadIdx.x == 255) bsum[blockIdx.x] = s[255];
}

__global__ void k_scanb(int* __restrict__ bsum, int nb) {
    __shared__ int s[256];
    int v = ((int)threadIdx.x < nb) ? bsum[threadIdx.x] : 0;
    s[threadIdx.x] = v;
    __syncthreads();
    for (int off = 1; off < 256; off <<= 1) {
        int t = (threadIdx.x >= off) ? s[threadIdx.x - off] : 0;
        __syncthreads();
        s[threadIdx.x] += t;
        __syncthreads();
    }
    if ((int)threadIdx.x < nb) bsum[threadIdx.x] = s[threadIdx.x] - v;  // exclusive
}

__global__ void k_scanc(const int* __restrict__ deg, const int* __restrict__ bsum,
                        int* __restrict__ off_, int* __restrict__ cursor, int n) {
    int i = blockIdx.x * blockDim.x + threadIdx.x;
    if (i < n) {
        int incl = off_[i + 1] + bsum[i >> 8];
        off_[i + 1] = incl;
        cursor[i] = incl - deg[i];
    }
    if (i == 0) off_[0] = 0;
}

// ---------------- scatter: payload {src*64, A, B, 0} ----------------
__global__ void k_scatter(const int* __restrict__ src, const int* __restrict__ dst,
                          const float* __restrict__ dist, int* __restrict__ cursor,
                          int4* __restrict__ psort, int n_edges) {
    int e = blockIdx.x * blockDim.x + threadIdx.x;
    if (e >= n_edges) return;
    int t = dst[e];
    int pos = atomicAdd(&cursor[t], 1);
    float d = dist[e];
    float A = __expf(-1.125f * d * d);
    float B = __expf(1.5f * d);
    psort[pos] = make_int4(src[e] << 6, __float_as_int(A), __float_as_int(B), 0);
}

// ---------------- conv (+ fused next-layer gemm) ----------------
__global__ __launch_bounds__(256, 6) void k_conv(
        const int4* __restrict__ ps, const int* __restrict__ off,
        const __half* __restrict__ h,
        const float* __restrict__ We, const float* __restrict__ be,
        const float* __restrict__ W2, const float* __restrict__ b2,
        const float* __restrict__ W1n, const float* __restrict__ b1n,
        float* __restrict__ x, __half* __restrict__ hout,
        int n_nodes, int do_next) {
    int lane = threadIdx.x & 63;
    int gw = __builtin_amdgcn_readfirstlane((blockIdx.x * blockDim.x + threadIdx.x) >> 6);
    int nw = (gridDim.x * blockDim.x) >> 6;

    const float C[10] = {RBF_C0, RBF_C1, RBF_C2, RBF_C3, RBF_C4,
                         RBF_C5, RBF_C6, RBF_C7, RBF_C8, RBF_C9};
    float wp[10];
#pragma unroll
    for (int r = 0; r < 10; ++r) wp[r] = We[r * 64 + lane] * C[r];
    float bj  = be[lane];
    float b2j = b2[lane];
    float b1j = do_next ? b1n[lane] : 0.0f;

    for (int n = gw; n < n_nodes; n += nw) {
        int k0 = off[n], k1 = off[n + 1];
        float acc = 0.0f;
        int k = k0;
        for (; k + 8 <= k1; k += 8) {   // 8 gathers in flight
            int4 p0 = ps[k + 0], p1 = ps[k + 1], p2 = ps[k + 2], p3 = ps[k + 3];
            int4 p4 = ps[k + 4], p5 = ps[k + 5], p6 = ps[k + 6], p7 = ps[k + 7];
            float g0 = __half2float(h[p0.x + lane]);
            float g1 = __half2float(h[p1.x + lane]);
            float g2 = __half2float(h[p2.x + lane]);
            float g3 = __half2float(h[p3.x + lane]);
            float g4 = __half2float(h[p4.x + lane]);
            float g5 = __half2float(h[p5.x + lane]);
            float g6 = __half2float(h[p6.x + lane]);
            float g7 = __half2float(h[p7.x + lane]);
            acc = fmaf(g0, filt_ab(wp, bj, __int_as_float(p0.y), __int_as_float(p0.z)), acc);
            acc = fmaf(g1, filt_ab(wp, bj, __int_as_float(p1.y), __int_as_float(p1.z)), acc);
            acc = fmaf(g2, filt_ab(wp, bj, __int_as_float(p2.y), __int_as_float(p2.z)), acc);
            acc = fmaf(g3, filt_ab(wp, bj, __int_as_float(p3.y), __int_as_float(p3.z)), acc);
            acc = fmaf(g4, filt_ab(wp, bj, __int_as_float(p4.y), __int_as_float(p4.z)), acc);
            acc = fmaf(g5, filt_ab(wp, bj, __int_as_float(p5.y), __int_as_float(p5.z)), acc);
            acc = fmaf(g6, filt_ab(wp, bj, __int_as_float(p6.y), __int_as_float(p6.z)), acc);
            acc = fmaf(g7, filt_ab(wp, bj, __int_as_float(p7.y), __int_as_float(p7.z)), acc);
        }
        for (; k + 4 <= k1; k += 4) {
            int4 p0 = ps[k + 0], p1 = ps[k + 1], p2 = ps[k + 2], p3 = ps[k + 3];
            float g0 = __half2float(h[p0.x + lane]);
            float g1 = __half2float(h[p1.x + lane]);
            float g2 = __half2float(h[p2.x + lane]);
            float g3 = __half2float(h[p3.x + lane]);
            acc = fmaf(g0, filt_ab(wp, bj, __int_as_float(p0.y), __int_as_float(p0.z)), acc);
            acc = fmaf(g1, filt_ab(wp, bj, __int_as_float(p1.y), __int_as_float(p1.z)), acc);
            acc = fmaf(g2, filt_ab(wp, bj, __int_as_float(p2.y), __int_as_float(p2.z)), acc);
            acc = fmaf(g3, filt_ab(wp, bj, __int_as_float(p3.y), __int_as_float(p3.z)), acc);
        }
        for (; k < k1; ++k) {
            int4 p = ps[k];
            float g = __half2float(h[p.x + lane]);
            acc = fmaf(g, filt_ab(wp, bj, __int_as_float(p.y), __int_as_float(p.z)), acc);
        }
        // x_new = softplus(x + b2 + acc @ W2)   (W2 reads are L1-resident)
        float o0 = b2j + x[n * 64 + lane];
        float o1 = 0.f, o2 = 0.f, o3 = 0.f;
#pragma unroll 4
        for (int kk = 0; kk < 16; ++kk) {
            o0 = fmaf(__shfl(acc, kk),      W2[(kk)      * 64 + lane], o0);
            o1 = fmaf(__shfl(acc, kk + 16), W2[(kk + 16) * 64 + lane], o1);
            o2 = fmaf(__shfl(acc, kk + 32), W2[(kk + 32) * 64 + lane], o2);
            o3 = fmaf(__shfl(acc, kk + 48), W2[(kk + 48) * 64 + lane], o3);
        }
        float xn = softplusf((o0 + o1) + (o2 + o3));
        x[n * 64 + lane] = xn;
        if (do_next) {  // h_next = x_new @ W1' + b1'  (row lives in the wave)
            float q0 = b1j, q1 = 0.f, q2 = 0.f, q3 = 0.f;
#pragma unroll 4
            for (int kk = 0; kk < 16; ++kk) {
                q0 = fmaf(__shfl(xn, kk),      W1n[(kk)      * 64 + lane], q0);
                q1 = fmaf(__shfl(xn, kk + 16), W1n[(kk + 16) * 64 + lane], q1);
                q2 = fmaf(__shfl(xn, kk + 32), W1n[(kk + 32) * 64 + lane], q2);
                q3 = fmaf(__shfl(xn, kk + 48), W1n[(kk + 48) * 64 + lane], q3);
            }
            hout[n * 64 + lane] = __float2half((q0 + q1) + (q2 + q3));
        }
    }
}

// ---------------- fused pool + head: one block per graph ----------------
__global__ void k_poolhead(const float* __restrict__ x, const int* __restrict__ gstart,
                           const float* __restrict__ Ws, const float* __restrict__ bs,
                           const float* __restrict__ Wbg1, const float* __restrict__ bbg1,
                           const float* __restrict__ Wbg2, const float* __restrict__ bbg2,
                           const float* __restrict__ Weh1, const float* __restrict__ beh1,
                           const float* __restrict__ Weh2, const float* __restrict__ beh2,
                           float* __restrict__ out, int n_graphs) {
    __shared__ float red[256];
    __shared__ float c[64];
    __shared__ float h1[128];
    int g = blockIdx.x;
    int t = threadIdx.x, j = t & 63, part = t >> 6;
    int s0 = gstart[g], s1 = gstart[g + 1];
    float acc = 0.0f;
    for (int n = s0 + part; n < s1; n += 4) acc += x[n * 64 + j];
    red[t] = acc;
    __syncthreads();
    if (part == 0)
        c[j] = (red[j] + red[64 + j] + red[128 + j] + red[192 + j]) /
               fmaxf((float)(s1 - s0), 1.0f);
    __syncthreads();
    if (t < 128) {
        float av = bs[t];
#pragma unroll 8
        for (int k = 0; k < 64; ++k) av = fmaf(c[k], Ws[k * 128 + t], av);
        h1[t] = fmaxf(av, 0.0f);
    }
    __syncthreads();
    if (t < 128) {
        const float* W1p = (t < 64) ? Wbg1 : Weh1;
        const float* b1p = (t < 64) ? bbg1 : beh1;
        const float* W2p = (t < 64) ? Wbg2 : Weh2;
        float b2v = (t < 64) ? bbg2[0] : beh2[0];
        int ln = t & 63;
        float a2 = b1p[ln];
#pragma unroll 8
        for (int k = 0; k < 128; ++k) a2 = fmaf(h1[k], W1p[k * 64 + ln], a2);
        a2 = fmaxf(a2, 0.0f);
        float pr = a2 * W2p[ln];
#pragma unroll
        for (int off = 32; off > 0; off >>= 1) pr += __shfl_down(pr, off);
        if (ln == 0) out[(t < 64 ? 0 : n_graphs) + g] = pr + b2v;
    }
}

extern "C" void kernel_launch(void* const* d_in, const int* in_sizes, int n_in,
                              void* d_out, int out_size, void* d_ws, size_t ws_size,
                              hipStream_t stream) {
    const int*   x_ids = (const int*)d_in[0];
    const int*   eidx  = (const int*)d_in[1];
    const float* eattr = (const float*)d_in[2];
    const int*   batch = (const int*)d_in[3];
    const float* emb   = (const float*)d_in[4];
    const float* W1    = (const float*)d_in[5];
    const float* b1    = (const float*)d_in[6];
    const float* We    = (const float*)d_in[7];
    const float* be    = (const float*)d_in[8];
    const float* W2    = (const float*)d_in[9];
    const float* b2    = (const float*)d_in[10];
    const float* Ws_   = (const float*)d_in[11];
    const float* bs_   = (const float*)d_in[12];
    const float* Wbg1  = (const float*)d_in[13];
    const float* bbg1  = (const float*)d_in[14];
    const float* Wbg2  = (const float*)d_in[15];
    const float* bbg2  = (const float*)d_in[16];
    const float* Weh1  = (const float*)d_in[17];
    const float* beh1  = (const float*)d_in[18];
    const float* Weh2  = (const float*)d_in[19];
    const float* beh2  = (const float*)d_in[20];

    int n_nodes  = in_sizes[0];
    int n_edges  = in_sizes[2];
    int n_graphs = out_size / 2;
    const int* src = eidx;
    const int* dst = eidx + n_edges;

    char* p = (char*)d_ws;
    float* x     = (float*)p;   p += (size_t)n_nodes * 64 * sizeof(float);
    __half* hA   = (__half*)p;  p += (size_t)n_nodes * 64 * sizeof(__half);
    __half* hB   = (__half*)p;  p += (size_t)n_nodes * 64 * sizeof(__half);
    int4* psort  = (int4*)p;    p += (size_t)n_edges * sizeof(int4);
    int* deg     = (int*)p;     p += (size_t)n_nodes * sizeof(int);
    int* off_    = (int*)p;     p += (size_t)(n_nodes + 1) * sizeof(int);
    int* cursor  = (int*)p;     p += (size_t)n_nodes * sizeof(int);
    int* bsum    = (int*)p;     p += 256 * sizeof(int);
    int* gstart  = (int*)p;     p += (size_t)(n_graphs + 1) * sizeof(int);
    float* out   = (float*)d_out;

    int nchunks = (n_nodes + 255) / 256;
    int nbE = (n_edges + 255) / 256;
    int nbN = (n_nodes + 255) / 256;

    hipMemsetAsync(deg, 0, (size_t)n_nodes * sizeof(int), stream);
    k_pre<<<nbE, 256, 0, stream>>>(dst, deg, batch, gstart, x_ids, emb, W1, b1,
                                   x, hA, n_edges, n_nodes, n_graphs);
    k_scana<<<nchunks, 256, 0, stream>>>(deg, off_, bsum, n_nodes);
    k_scanb<<<1, 256, 0, stream>>>(bsum, nchunks);
    k_scanc<<<nbN, 256, 0, stream>>>(deg, bsum, off_, cursor, n_nodes);
    k_scatter<<<nbE, 256, 0, stream>>>(src, dst, eattr, cursor, psort, n_edges);

    // conv(l): reads h_in, writes x and (l<2) h_out = x_new @ W1[l+1] + b1[l+1]
    k_conv<<<4096, 256, 0, stream>>>(psort, off_, hA, We, be, W2, b2,
                                     W1 + 4096, b1 + 64, x, hB, n_nodes, 1);
    k_conv<<<4096, 256, 0, stream>>>(psort, off_, hB, We + 640, be + 64,
                                     W2 + 4096, b2 + 64,
                                     W1 + 8192, b1 + 128, x, hA, n_nodes, 1);
    k_conv<<<4096, 256, 0, stream>>>(psort, off_, hA, We + 1280, be + 128,
                                     W2 + 8192, b2 + 128,
                                     nullptr, nullptr, x, nullptr, n_nodes, 0);

    k_poolhead<<<n_graphs, 256, 0, stream>>>(x, gstart, Ws_, bs_, Wbg1, bbg1, Wbg2, bbg2,
                                             Weh1, beh1, Weh2, beh2, out, n_graphs);
}